// Round 4
// baseline (654.708 us; speedup 1.0000x reference)
//
#include <hip/hip_runtime.h>

#define NN 50000
#define NPAD 50048          // 782 * 64
#define D 512

typedef __attribute__((ext_vector_type(4))) float f32x4;
typedef __attribute__((ext_vector_type(8))) short bf16x8;

__device__ __forceinline__ float bf2f(unsigned short u) {
    return __uint_as_float(((unsigned int)u) << 16);
}
__device__ __forceinline__ unsigned short f2bf(float f) {
    unsigned int x = __float_as_uint(f);
    return (unsigned short)((x + 0x7fffu + ((x >> 16) & 1u)) >> 16);
}

// ---------------------------------------------------------------------------
// Numerical collapse (verified rounds 2-3, absmax <= 0.0078): global-Frobenius
// normalization makes the low-rank attention terms ~2e-9 relative =>
// full_attention_conv(q,k,v) == v, trans_layer(h) == h @ mean_heads(Wv)+b̄v.
// Net: h=relu(LN(gnn_x@fc0+b0)); h=LN(.5(h@Wm_L+bm_L)+.5h) x2; out=h@(wr@fc)+fc_b
//
// Round-4 structure note: NO LDS in the GEMM main loop. MFMA A/B fragments are
// 16B-contiguous in memory (A row-major [row][k], Wt col-major [col][k]) and
// loaded straight to VGPRs. B (512KB) is L2-resident across all 782 blocks;
// A rows are L1-shared by the 8 column-waves of a block. This removes the
// per-K-step __syncthreads + vmcnt(0) staging drain that capped round 3
// (MfmaUtil 10%, occupancy 17%, 100us/dispatch vs 16us memory floor).
// ---------------------------------------------------------------------------

// Fused GEMM(64 rows x 512 cols, K=512) + bias + [0.5 mix residual] + LN + [relu].
// 8 waves; wave w owns cols [w*64, w*64+64). MODE 0: LN+relu -> bf16.
// MODE 1: 0.5 mix + LN -> bf16. MODE 2: acc+bias -> f32.
template<int MODE>
__global__ __launch_bounds__(512, 4)
void fused_gemm_ln(const unsigned short* __restrict__ Abf,
                   const unsigned short* __restrict__ Wt,
                   const float* __restrict__ bias,
                   const float* __restrict__ g, const float* __restrict__ bln,
                   unsigned short* __restrict__ outB, float* __restrict__ outF)
{
    __shared__ float Sred[512], Qred[512], MUs[64], RSs[64];

    const int tid = threadIdx.x;
    const int w = tid >> 6, l = tid & 63;
    const int l15 = l & 15, lhi = l >> 4;
    const int row0 = blockIdx.x * 64;

    // per-lane fragment base pointers (16B-aligned contiguous loads)
    const unsigned short* aBase = Abf + (size_t)(row0 + l15) * D + lhi * 8;
    const unsigned short* bBase = Wt + (size_t)(w * 64 + l15) * D + lhi * 8;

    f32x4 acc[4][4] = {};
    for (int k0 = 0; k0 < 512; k0 += 32) {
        bf16x8 af[4], bfr[4];
        #pragma unroll
        for (int rf = 0; rf < 4; ++rf)
            af[rf] = *(const bf16x8*)(aBase + (size_t)rf * 16 * D + k0);
        #pragma unroll
        for (int cf = 0; cf < 4; ++cf)
            bfr[cf] = *(const bf16x8*)(bBase + (size_t)cf * 16 * D + k0);
        #pragma unroll
        for (int rf = 0; rf < 4; ++rf)
            #pragma unroll
            for (int cf = 0; cf < 4; ++cf)
                acc[rf][cf] = __builtin_amdgcn_mfma_f32_16x16x32_bf16(
                    af[rf], bfr[cf], acc[rf][cf], 0, 0, 0);
    }

    // ---- epilogue: D layout col = lane&15, row = (lane>>4)*4 + reg (m89) ----
    float bia[4];
    int ccol[4];
    #pragma unroll
    for (int cf = 0; cf < 4; ++cf) {
        ccol[cf] = w * 64 + cf * 16 + l15;
        bia[cf] = bias[ccol[cf]];
    }

    if (MODE == 2) {
        #pragma unroll
        for (int rf = 0; rf < 4; ++rf)
            #pragma unroll
            for (int reg = 0; reg < 4; ++reg) {
                const int r = row0 + rf * 16 + lhi * 4 + reg;
                if (r < NN) {
                    #pragma unroll
                    for (int cf = 0; cf < 4; ++cf)
                        outF[(size_t)r * D + ccol[cf]] = acc[rf][cf][reg] + bia[cf];
                }
            }
        return;
    }

    // z = acc + bias (MODE 0) or 0.5*(acc+bias) + 0.5*resid (MODE 1)
    #pragma unroll
    for (int rf = 0; rf < 4; ++rf)
        #pragma unroll
        for (int cf = 0; cf < 4; ++cf)
            #pragma unroll
            for (int reg = 0; reg < 4; ++reg) {
                float z = acc[rf][cf][reg] + bia[cf];
                if (MODE == 1) {
                    const int r = row0 + rf * 16 + lhi * 4 + reg;   // < NPAD, in-bounds
                    z = 0.5f * z + 0.5f * bf2f(Abf[(size_t)r * D + ccol[cf]]);
                }
                acc[rf][cf][reg] = z;
            }

    // per-row sum/sumsq: 4 cols in-reg, 16 lanes via shfl_xor, 8 waves via LDS
    #pragma unroll
    for (int rf = 0; rf < 4; ++rf)
        #pragma unroll
        for (int reg = 0; reg < 4; ++reg) {
            float s = acc[rf][0][reg] + acc[rf][1][reg] + acc[rf][2][reg] + acc[rf][3][reg];
            float q2 = acc[rf][0][reg] * acc[rf][0][reg] + acc[rf][1][reg] * acc[rf][1][reg]
                     + acc[rf][2][reg] * acc[rf][2][reg] + acc[rf][3][reg] * acc[rf][3][reg];
            #pragma unroll
            for (int m = 1; m < 16; m <<= 1) {
                s += __shfl_xor(s, m, 64);
                q2 += __shfl_xor(q2, m, 64);
            }
            if (l15 == 0) {
                const int rl = rf * 16 + lhi * 4 + reg;
                Sred[w * 64 + rl] = s;
                Qred[w * 64 + rl] = q2;
            }
        }
    __syncthreads();
    if (tid < 64) {
        float s = 0.f, q2 = 0.f;
        #pragma unroll
        for (int ww = 0; ww < 8; ++ww) { s += Sred[ww * 64 + tid]; q2 += Qred[ww * 64 + tid]; }
        const float mu = s * (1.f / 512.f);
        MUs[tid] = mu;
        RSs[tid] = rsqrtf(q2 * (1.f / 512.f) - mu * mu + 1e-5f);
    }
    __syncthreads();

    float gg[4], bbv[4];
    #pragma unroll
    for (int cf = 0; cf < 4; ++cf) { gg[cf] = g[ccol[cf]]; bbv[cf] = bln[ccol[cf]]; }
    #pragma unroll
    for (int rf = 0; rf < 4; ++rf)
        #pragma unroll
        for (int reg = 0; reg < 4; ++reg) {
            const int rl = rf * 16 + lhi * 4 + reg;
            const int r = row0 + rl;
            if (r >= NN) continue;
            const float mu = MUs[rl], rs = RSs[rl];
            #pragma unroll
            for (int cf = 0; cf < 4; ++cf) {
                float y = (acc[rf][cf][reg] - mu) * rs * gg[cf] + bbv[cf];
                if (MODE == 0) y = fmaxf(y, 0.f);
                outB[(size_t)r * D + ccol[cf]] = f2bf(y);
            }
        }
}

// ---- setup kernels (tiny, perf-irrelevant) ----

__global__ __launch_bounds__(256)
void cvt_f32_bf16(const float* __restrict__ x, unsigned short* __restrict__ o, long long n8)
{
    const long long stride = (long long)gridDim.x * 256;
    for (long long i = (long long)blockIdx.x * 256 + threadIdx.x; i < n8; i += stride) {
        const float4 a = ((const float4*)x)[2 * i];
        const float4 b = ((const float4*)x)[2 * i + 1];
        uint4 u;
        u.x = (unsigned)f2bf(a.x) | ((unsigned)f2bf(a.y) << 16);
        u.y = (unsigned)f2bf(a.z) | ((unsigned)f2bf(a.w) << 16);
        u.z = (unsigned)f2bf(b.x) | ((unsigned)f2bf(b.y) << 16);
        u.w = (unsigned)f2bf(b.z) | ((unsigned)f2bf(b.w) << 16);
        ((uint4*)o)[i] = u;
    }
}

// Wt[c][k] = bf16(W[k][c])
__global__ __launch_bounds__(256)
void transpose_cvt(const float* __restrict__ Wf, unsigned short* __restrict__ Wt)
{
    const int c = blockIdx.x;
    for (int k = threadIdx.x; k < 512; k += 256)
        Wt[(size_t)c * 512 + k] = f2bf(Wf[(size_t)k * 512 + c]);
}

// Wmt[d][j] = bf16(0.5*(wv[j][d] + wv[j][512+d]))
__global__ __launch_bounds__(256)
void fold_wv_t(const float* __restrict__ wv, unsigned short* __restrict__ Wmt)
{
    const int d = blockIdx.x;
    for (int j = threadIdx.x; j < 512; j += 256)
        Wmt[(size_t)d * 512 + j] =
            f2bf(0.5f * (wv[(size_t)j * 1024 + d] + wv[(size_t)j * 1024 + 512 + d]));
}

__global__ __launch_bounds__(256)
void fold_bias(const float* __restrict__ bv0, const float* __restrict__ bv1,
               float* __restrict__ bm)
{
    const int d = blockIdx.x * 256 + threadIdx.x;
    if (d < 512) {
        bm[d]       = 0.5f * (bv0[d] + bv0[512 + d]);
        bm[512 + d] = 0.5f * (bv1[d] + bv1[512 + d]);
    }
}

#define FMA16(acc, a4, w4) \
    acc[0][0] += a4.x*w4.x; acc[0][1] += a4.x*w4.y; acc[0][2] += a4.x*w4.z; acc[0][3] += a4.x*w4.w; \
    acc[1][0] += a4.y*w4.x; acc[1][1] += a4.y*w4.y; acc[1][2] += a4.y*w4.z; acc[1][3] += a4.y*w4.w; \
    acc[2][0] += a4.z*w4.x; acc[2][1] += a4.z*w4.y; acc[2][2] += a4.z*w4.z; acc[2][3] += a4.z*w4.w; \
    acc[3][0] += a4.w*w4.x; acc[3][1] += a4.w*w4.y; acc[3][2] += a4.w*w4.z; acc[3][3] += a4.w*w4.w;

// small f32 GEMM (512x512x512), only for Wrf = wr@fc
__global__ __launch_bounds__(256)
void gemm_f32(const float* __restrict__ A, const float* __restrict__ W,
              float* __restrict__ Cout)
{
    __shared__ __align__(16) float As[16][68];
    __shared__ __align__(16) float Ws[16][64];
    const int row0 = blockIdx.x * 64, c0 = blockIdx.y * 64;
    const int tid = threadIdx.x;
    const int tx = tid & 15, ty = tid >> 4;
    const int lrow = tid >> 2, lk4 = (tid & 3) << 2;
    const int wk = tid >> 4, wc4 = (tid & 15) << 2;
    float acc[4][4] = {};
    for (int k0 = 0; k0 < 512; k0 += 16) {
        const float4 av = *reinterpret_cast<const float4*>(A + (size_t)(row0 + lrow) * 512 + k0 + lk4);
        const float4 wv = *reinterpret_cast<const float4*>(W + (size_t)(k0 + wk) * 512 + c0 + wc4);
        __syncthreads();
        As[lk4 + 0][lrow] = av.x; As[lk4 + 1][lrow] = av.y;
        As[lk4 + 2][lrow] = av.z; As[lk4 + 3][lrow] = av.w;
        *reinterpret_cast<float4*>(&Ws[wk][wc4]) = wv;
        __syncthreads();
        #pragma unroll
        for (int kk = 0; kk < 16; ++kk) {
            const float4 a4 = *reinterpret_cast<const float4*>(&As[kk][ty << 2]);
            const float4 w4 = *reinterpret_cast<const float4*>(&Ws[kk][tx << 2]);
            FMA16(acc, a4, w4)
        }
    }
    #pragma unroll
    for (int i = 0; i < 4; ++i)
        *reinterpret_cast<float4*>(Cout + (size_t)(row0 + (ty << 2) + i) * 512 + c0 + (tx << 2)) =
            make_float4(acc[i][0], acc[i][1], acc[i][2], acc[i][3]);
}

extern "C" void kernel_launch(void* const* d_in, const int* in_sizes, int n_in,
                              void* d_out, int out_size, void* d_ws, size_t ws_size,
                              hipStream_t stream)
{
    const float* gnn_x = (const float*)d_in[1];
    const float* fc0_w = (const float*)d_in[4];
    const float* fc0_b = (const float*)d_in[5];
    const float* ln0_g = (const float*)d_in[6];
    const float* ln0_b = (const float*)d_in[7];
    const float* wv_w[2] = {(const float*)d_in[12], (const float*)d_in[20]};
    const float* wv_b[2] = {(const float*)d_in[13], (const float*)d_in[21]};
    const float* lng[2]  = {(const float*)d_in[14], (const float*)d_in[22]};
    const float* lnb[2]  = {(const float*)d_in[15], (const float*)d_in[23]};
    const float* wr_w = (const float*)d_in[24];
    const float* fc_w = (const float*)d_in[25];
    const float* fc_b = (const float*)d_in[26];

    // workspace ~53.4 MB
    char* ws = (char*)d_ws;
    size_t off = 0;
    auto alloc = [&](size_t bytes) -> void* {
        void* p = ws + off;
        off += (bytes + 255) & ~(size_t)255;
        return p;
    };
    unsigned short* h   = (unsigned short*)alloc((size_t)NPAD * D * 2);
    unsigned short* W0t = (unsigned short*)alloc((size_t)D * D * 2);
    unsigned short* W1t = (unsigned short*)alloc((size_t)D * D * 2);
    unsigned short* W2t = (unsigned short*)alloc((size_t)D * D * 2);
    unsigned short* W3t = (unsigned short*)alloc((size_t)D * D * 2);
    float*          bm  = (float*)alloc((size_t)2 * D * 4);
    float*          Wrf = (float*)d_out;   // f32 512x512 scratch; d_out rewritten later

    const dim3 blk256(256), blk512(512);
    const int rowTiles = NPAD / 64;        // 782

    // setup
    cvt_f32_bf16<<<dim3(2048), blk256, 0, stream>>>(gnn_x, h, (long long)NN * D / 8);
    transpose_cvt<<<dim3(512), blk256, 0, stream>>>(fc0_w, W0t);
    fold_wv_t<<<dim3(512), blk256, 0, stream>>>(wv_w[0], W1t);
    fold_wv_t<<<dim3(512), blk256, 0, stream>>>(wv_w[1], W2t);
    fold_bias<<<dim3(2), blk256, 0, stream>>>(wv_b[0], wv_b[1], bm);
    gemm_f32<<<dim3(8, 8), blk256, 0, stream>>>(wr_w, fc_w, Wrf);
    transpose_cvt<<<dim3(512), blk256, 0, stream>>>(Wrf, W3t);

    // h = relu(LN(gnn_x@fc0 + b0))   (in place: each block touches only its rows)
    fused_gemm_ln<0><<<dim3(rowTiles), blk512, 0, stream>>>(
        h, W0t, fc0_b, ln0_g, ln0_b, h, nullptr);
    // h = LN(0.5*(h@Wm_L + bm_L) + 0.5*h) x2
    fused_gemm_ln<1><<<dim3(rowTiles), blk512, 0, stream>>>(
        h, W1t, bm, lng[0], lnb[0], h, nullptr);
    fused_gemm_ln<1><<<dim3(rowTiles), blk512, 0, stream>>>(
        h, W2t, bm + D, lng[1], lnb[1], h, nullptr);
    // out = h @ (wr@fc) + fc_b
    fused_gemm_ln<2><<<dim3(rowTiles), blk512, 0, stream>>>(
        h, W3t, fc_b, nullptr, nullptr, nullptr, (float*)d_out);
}

// Round 5
// 419.977 us; speedup vs baseline: 1.5589x; 1.5589x over previous
//
#include <hip/hip_runtime.h>

#define NN 50000
#define D 512
#define DD (512 * 512)

typedef __attribute__((ext_vector_type(4))) float f32x4;
typedef __attribute__((ext_vector_type(8))) short bf16x8;

__device__ __forceinline__ float bf2f(unsigned short u) {
    return __uint_as_float(((unsigned int)u) << 16);
}
__device__ __forceinline__ unsigned short f2bf(float f) {
    unsigned int x = __float_as_uint(f);
    return (unsigned short)((x + 0x7fffu + ((x >> 16) & 1u)) >> 16);
}
// swizzled LDS position (ushort index) for h-tile element (row, k):
// 16B-unit q = k>>3, q' = q ^ (row&7)  -> ds_read_b128 per 16-lane quarter is <=2-way (free)
__device__ __forceinline__ int hpos(int row, int k) {
    return (row << 9) + (((k >> 3) ^ (row & 7)) << 3) + (k & 7);
}

// ---------------------------------------------------------------------------
// Numerical collapse (verified r2-r4, absmax <= 0.0078): global-Frobenius
// normalization makes the low-rank attention terms ~2e-9 relative =>
// full_attention_conv(q,k,v) == v, trans_layer(h) == h @ mean_heads(Wv)+b̄v.
// Net: h=relu(LN(gnn_x@fc0+b0)); h=LN(h@Wm_L+bm_L+h)[eps*4] x2; out=h@(wr@fc)+fc_b
// (LN scale-invariance: LN(0.5(a+h), eps) == LN(a+h, 4*eps).)
//
// Round-5 structure: the net is ROW-PARALLEL -> one block carries its 64 rows
// through all 4 GEMMs + 3 LNs entirely in LDS. A-tile staged once (swizzled,
// conflict-free ds_read_b128); B-fragments read direct from L2-resident 512KB
// weights (1-step prefetch, no barriers in K-loop). Kills r3's per-K-step
// vmcnt(0) barrier drain AND r4's A re-fetch from HBM (FETCH 82MB->~105MB tot).
// ---------------------------------------------------------------------------

__global__ __launch_bounds__(1024, 4)
void sg_fused(const float* __restrict__ X, const unsigned short* __restrict__ Wall,
              const float* __restrict__ b0, const float* __restrict__ g0, const float* __restrict__ v0,
              const float* __restrict__ bm, const float* __restrict__ g1, const float* __restrict__ v1,
              const float* __restrict__ g2, const float* __restrict__ v2,
              const float* __restrict__ fcb, float* __restrict__ out)
{
    __shared__ __align__(16) unsigned short hT[64 * 512];        // 64KB bf16 row-tile
    __shared__ float Sred[1024], Qred[1024], MUs[64], RSs[64];

    const int tid = threadIdx.x;
    const int w = tid >> 6, l = tid & 63, l15 = l & 15, lhi = l >> 4;
    const int row0 = blockIdx.x * 64;
    const int c0 = w * 32 + l15, c1 = c0 + 16;   // this wave's two 16-col groups

    // ---- stage gnn_x (f32) -> bf16 swizzled LDS, fully coalesced ----
    #pragma unroll
    for (int p = 0; p < 4; ++p) {
        const int u = tid + p * 1024;            // 4096 16B-units: row = u>>6, q = u&63
        const int row = u >> 6, q = u & 63;
        bf16x8 hv = {};
        if (row0 + row < NN) {
            const float* gp = X + (size_t)(row0 + row) * D + q * 8;
            const float4 f0 = *(const float4*)gp;
            const float4 f1 = *(const float4*)(gp + 4);
            hv[0] = (short)f2bf(f0.x); hv[1] = (short)f2bf(f0.y);
            hv[2] = (short)f2bf(f0.z); hv[3] = (short)f2bf(f0.w);
            hv[4] = (short)f2bf(f1.x); hv[5] = (short)f2bf(f1.y);
            hv[6] = (short)f2bf(f1.z); hv[7] = (short)f2bf(f1.w);
        }
        *(bf16x8*)&hT[(row << 9) + ((q ^ (row & 7)) << 3)] = hv;
    }
    __syncthreads();

    // ---- GEMM main loop: A from LDS, B direct from global (L2-hot), no barriers ----
    auto gemm = [&](const unsigned short* __restrict__ Wt, f32x4 acc[4][2]) {
        const unsigned short* bp0 = Wt + (size_t)c0 * D + lhi * 8;
        const unsigned short* bp1 = Wt + (size_t)c1 * D + lhi * 8;
        bf16x8 bc0 = *(const bf16x8*)bp0;
        bf16x8 bc1 = *(const bf16x8*)bp1;
        const int sw = l15 & 7;
        #pragma unroll 4
        for (int k0 = 0; k0 < 512; k0 += 32) {
            bf16x8 bn0 = bc0, bn1 = bc1;
            if (k0 < 480) {
                bn0 = *(const bf16x8*)(bp0 + k0 + 32);
                bn1 = *(const bf16x8*)(bp1 + k0 + 32);
            }
            const int q = (k0 >> 3) + lhi;
            const int su = (q ^ sw) << 3;
            bf16x8 af0 = *(const bf16x8*)&hT[((l15     ) << 9) + su];
            bf16x8 af1 = *(const bf16x8*)&hT[((l15 + 16) << 9) + su];
            bf16x8 af2 = *(const bf16x8*)&hT[((l15 + 32) << 9) + su];
            bf16x8 af3 = *(const bf16x8*)&hT[((l15 + 48) << 9) + su];
            acc[0][0] = __builtin_amdgcn_mfma_f32_16x16x32_bf16(af0, bc0, acc[0][0], 0, 0, 0);
            acc[0][1] = __builtin_amdgcn_mfma_f32_16x16x32_bf16(af0, bc1, acc[0][1], 0, 0, 0);
            acc[1][0] = __builtin_amdgcn_mfma_f32_16x16x32_bf16(af1, bc0, acc[1][0], 0, 0, 0);
            acc[1][1] = __builtin_amdgcn_mfma_f32_16x16x32_bf16(af1, bc1, acc[1][1], 0, 0, 0);
            acc[2][0] = __builtin_amdgcn_mfma_f32_16x16x32_bf16(af2, bc0, acc[2][0], 0, 0, 0);
            acc[2][1] = __builtin_amdgcn_mfma_f32_16x16x32_bf16(af2, bc1, acc[2][1], 0, 0, 0);
            acc[3][0] = __builtin_amdgcn_mfma_f32_16x16x32_bf16(af3, bc0, acc[3][0], 0, 0, 0);
            acc[3][1] = __builtin_amdgcn_mfma_f32_16x16x32_bf16(af3, bc1, acc[3][1], 0, 0, 0);
            bc0 = bn0; bc1 = bn1;
        }
    };

    // ---- LN epilogue (D layout: col=lane&15 group, row=(lane>>4)*4+reg) + LDS write-back ----
    auto lnwr = [&](f32x4 acc[4][2], const float* bias, const float* g, const float* bv,
                    float eps, bool relu, bool resid) {
        const float bia0 = bias[c0], bia1 = bias[c1];
        #pragma unroll
        for (int rf = 0; rf < 4; ++rf)
            #pragma unroll
            for (int reg = 0; reg < 4; ++reg) {
                const int rowl = rf * 16 + lhi * 4 + reg;
                float z0 = acc[rf][0][reg] + bia0;
                float z1 = acc[rf][1][reg] + bia1;
                if (resid) {
                    z0 += bf2f(hT[hpos(rowl, c0)]);
                    z1 += bf2f(hT[hpos(rowl, c1)]);
                }
                acc[rf][0][reg] = z0;
                acc[rf][1][reg] = z1;
                float s = z0 + z1, q2 = z0 * z0 + z1 * z1;
                #pragma unroll
                for (int m = 1; m < 16; m <<= 1) {
                    s += __shfl_xor(s, m, 64);
                    q2 += __shfl_xor(q2, m, 64);
                }
                if (l15 == 0) { Sred[(w << 6) + rowl] = s; Qred[(w << 6) + rowl] = q2; }
            }
        __syncthreads();
        if (tid < 64) {
            float s = 0.f, q2 = 0.f;
            #pragma unroll
            for (int ww = 0; ww < 16; ++ww) { s += Sred[(ww << 6) + tid]; q2 += Qred[(ww << 6) + tid]; }
            const float mu = s * (1.f / 512.f);
            MUs[tid] = mu;
            RSs[tid] = rsqrtf(q2 * (1.f / 512.f) - mu * mu + eps);
        }
        __syncthreads();
        const float gg0 = g[c0], gg1 = g[c1], bv0 = bv[c0], bv1 = bv[c1];
        #pragma unroll
        for (int rf = 0; rf < 4; ++rf)
            #pragma unroll
            for (int reg = 0; reg < 4; ++reg) {
                const int rowl = rf * 16 + lhi * 4 + reg;
                const float mu = MUs[rowl], rs = RSs[rowl];
                float y0 = (acc[rf][0][reg] - mu) * rs * gg0 + bv0;
                float y1 = (acc[rf][1][reg] - mu) * rs * gg1 + bv1;
                if (relu) { y0 = fmaxf(y0, 0.f); y1 = fmaxf(y1, 0.f); }
                hT[hpos(rowl, c0)] = f2bf(y0);
                hT[hpos(rowl, c1)] = f2bf(y1);
            }
        __syncthreads();
    };

    { f32x4 acc[4][2] = {}; gemm(Wall,          acc); lnwr(acc, b0,     g0, v0, 1e-5f, true,  false); }
    { f32x4 acc[4][2] = {}; gemm(Wall + DD,     acc); lnwr(acc, bm,     g1, v1, 4e-5f, false, true);  }
    { f32x4 acc[4][2] = {}; gemm(Wall + 2 * DD, acc); lnwr(acc, bm + D, g2, v2, 4e-5f, false, true);  }
    {
        f32x4 acc[4][2] = {};
        gemm(Wall + 3 * DD, acc);
        const float bia0 = fcb[c0], bia1 = fcb[c1];
        #pragma unroll
        for (int rf = 0; rf < 4; ++rf)
            #pragma unroll
            for (int reg = 0; reg < 4; ++reg) {
                const int r = row0 + rf * 16 + lhi * 4 + reg;
                if (r < NN) {
                    out[(size_t)r * D + c0] = acc[rf][0][reg] + bia0;
                    out[(size_t)r * D + c1] = acc[rf][1][reg] + bia1;
                }
            }
    }
}

// ---- setup kernels (tiny) ----

// Wt[c][k] = bf16(W[k][c])
__global__ __launch_bounds__(256)
void transpose_cvt(const float* __restrict__ Wf, unsigned short* __restrict__ Wt)
{
    const int c = blockIdx.x;
    for (int k = threadIdx.x; k < 512; k += 256)
        Wt[(size_t)c * 512 + k] = f2bf(Wf[(size_t)k * 512 + c]);
}

// Wmt[d][j] = bf16(0.5*(wv[j][d] + wv[j][512+d]))
__global__ __launch_bounds__(256)
void fold_wv_t(const float* __restrict__ wv, unsigned short* __restrict__ Wmt)
{
    const int d = blockIdx.x;
    for (int j = threadIdx.x; j < 512; j += 256)
        Wmt[(size_t)d * 512 + j] =
            f2bf(0.5f * (wv[(size_t)j * 1024 + d] + wv[(size_t)j * 1024 + 512 + d]));
}

__global__ __launch_bounds__(256)
void fold_bias(const float* __restrict__ bv0, const float* __restrict__ bv1,
               float* __restrict__ bm)
{
    const int d = blockIdx.x * 256 + threadIdx.x;
    if (d < 512) {
        bm[d]       = 0.5f * (bv0[d] + bv0[512 + d]);
        bm[512 + d] = 0.5f * (bv1[d] + bv1[512 + d]);
    }
}

#define FMA16(acc, a4, w4) \
    acc[0][0] += a4.x*w4.x; acc[0][1] += a4.x*w4.y; acc[0][2] += a4.x*w4.z; acc[0][3] += a4.x*w4.w; \
    acc[1][0] += a4.y*w4.x; acc[1][1] += a4.y*w4.y; acc[1][2] += a4.y*w4.z; acc[1][3] += a4.y*w4.w; \
    acc[2][0] += a4.z*w4.x; acc[2][1] += a4.z*w4.y; acc[2][2] += a4.z*w4.z; acc[2][3] += a4.z*w4.w; \
    acc[3][0] += a4.w*w4.x; acc[3][1] += a4.w*w4.y; acc[3][2] += a4.w*w4.z; acc[3][3] += a4.w*w4.w;

// f32 GEMM 512x512x512, only for Wrf = wr@fc
__global__ __launch_bounds__(256)
void gemm_f32(const float* __restrict__ A, const float* __restrict__ W,
              float* __restrict__ Cout)
{
    __shared__ __align__(16) float As[16][68];
    __shared__ __align__(16) float Ws[16][64];
    const int row0 = blockIdx.x * 64, cB = blockIdx.y * 64;
    const int tid = threadIdx.x;
    const int tx = tid & 15, ty = tid >> 4;
    const int lrow = tid >> 2, lk4 = (tid & 3) << 2;
    const int wk = tid >> 4, wc4 = (tid & 15) << 2;
    float acc[4][4] = {};
    for (int k0 = 0; k0 < 512; k0 += 16) {
        const float4 av = *reinterpret_cast<const float4*>(A + (size_t)(row0 + lrow) * 512 + k0 + lk4);
        const float4 wv = *reinterpret_cast<const float4*>(W + (size_t)(k0 + wk) * 512 + cB + wc4);
        __syncthreads();
        As[lk4 + 0][lrow] = av.x; As[lk4 + 1][lrow] = av.y;
        As[lk4 + 2][lrow] = av.z; As[lk4 + 3][lrow] = av.w;
        *reinterpret_cast<float4*>(&Ws[wk][wc4]) = wv;
        __syncthreads();
        #pragma unroll
        for (int kk = 0; kk < 16; ++kk) {
            const float4 a4 = *reinterpret_cast<const float4*>(&As[kk][ty << 2]);
            const float4 w4 = *reinterpret_cast<const float4*>(&Ws[kk][tx << 2]);
            FMA16(acc, a4, w4)
        }
    }
    #pragma unroll
    for (int i = 0; i < 4; ++i)
        *reinterpret_cast<float4*>(Cout + (size_t)(row0 + (ty << 2) + i) * 512 + cB + (tx << 2)) =
            make_float4(acc[i][0], acc[i][1], acc[i][2], acc[i][3]);
}

extern "C" void kernel_launch(void* const* d_in, const int* in_sizes, int n_in,
                              void* d_out, int out_size, void* d_ws, size_t ws_size,
                              hipStream_t stream)
{
    const float* gnn_x = (const float*)d_in[1];
    const float* fc0_w = (const float*)d_in[4];
    const float* fc0_b = (const float*)d_in[5];
    const float* ln0_g = (const float*)d_in[6];
    const float* ln0_b = (const float*)d_in[7];
    const float* wv_w[2] = {(const float*)d_in[12], (const float*)d_in[20]};
    const float* wv_b[2] = {(const float*)d_in[13], (const float*)d_in[21]};
    const float* lng[2]  = {(const float*)d_in[14], (const float*)d_in[22]};
    const float* lnb[2]  = {(const float*)d_in[15], (const float*)d_in[23]};
    const float* wr_w = (const float*)d_in[24];
    const float* fc_w = (const float*)d_in[25];
    const float* fc_b = (const float*)d_in[26];

    // workspace ~2.1 MB
    char* ws = (char*)d_ws;
    size_t off = 0;
    auto alloc = [&](size_t bytes) -> void* {
        void* p = ws + off;
        off += (bytes + 255) & ~(size_t)255;
        return p;
    };
    unsigned short* Wall = (unsigned short*)alloc((size_t)4 * DD * 2);  // 4 bf16 [col][k] weights
    float*          bm   = (float*)alloc((size_t)2 * D * 4);
    float*          Wrf  = (float*)d_out;   // f32 512x512 scratch; overwritten by sg_fused

    const dim3 blk256(256);

    transpose_cvt<<<dim3(512), blk256, 0, stream>>>(fc0_w, Wall);
    fold_wv_t<<<dim3(512), blk256, 0, stream>>>(wv_w[0], Wall + DD);
    fold_wv_t<<<dim3(512), blk256, 0, stream>>>(wv_w[1], Wall + 2 * DD);
    fold_bias<<<dim3(2), blk256, 0, stream>>>(wv_b[0], wv_b[1], bm);
    gemm_f32<<<dim3(8, 8), blk256, 0, stream>>>(wr_w, fc_w, Wrf);
    transpose_cvt<<<dim3(512), blk256, 0, stream>>>(Wrf, Wall + 3 * DD);

    sg_fused<<<dim3((NN + 63) / 64), dim3(1024), 0, stream>>>(
        gnn_x, Wall,
        fc0_b, ln0_g, ln0_b,
        bm, lng[0], lnb[0],
        lng[1], lnb[1],
        fc_b, (float*)d_out);
}